// Round 10
// baseline (677.811 us; speedup 1.0000x reference)
//
#include <hip/hip_runtime.h>
#include <hip/hip_bf16.h>
#include <cstdint>

#define DEVI __device__ __forceinline__

typedef __attribute__((ext_vector_type(8))) short short8;
typedef __attribute__((ext_vector_type(4))) float f32x4;
typedef unsigned int u32;
typedef unsigned short u16;

DEVI u16 f2bf(float f) {
  __hip_bfloat16 h = __float2bfloat16(f);
  return *reinterpret_cast<u16*>(&h);
}

// async global->LDS, 16B per lane. LDS dest must be wave-uniform base + lane*16.
DEVI void async_cp16(const __hip_bfloat16* g, __hip_bfloat16* l) {
  __builtin_amdgcn_global_load_lds(
      (const __attribute__((address_space(1))) u32*)(uintptr_t)g,
      (__attribute__((address_space(3))) u32*)(uintptr_t)l, 16, 0, 0);
}

// XCD-affinity bijective block remap (PV only — measured r6: FETCH 148->74 MB):
// blocks sharing an A-panel (same y,z; all x) land on the SAME XCD at
// consecutive slots, so the panel is served from that XCD's L2 on re-reads.
// HW assigns xcd ~ dispatch_id % 8. Requires gy*gz % 8 == 0.
DEVI void xcd_remap(int& bx, int& by, int& bz) {
  const int gx = gridDim.x, gy = gridDim.y;
  const int d = blockIdx.x + gx * (blockIdx.y + gridDim.y * blockIdx.z);
  const int idx = d >> 3;
  const int g = (d & 7) + 8 * (idx / gx);
  bx = idx % gx;
  by = g % gy;
  bz = g / gy;
}

// T2 swizzle (rule #21: LDS linear for global_load_lds; SOURCE column group
// pre-swizzled; READ uses the same XOR): LDS[row][g] = A[row][g ^ (row&3)]
// (g = 16B k-group 0..3). Read of A[r][quad] -> group quad ^ (r&3); since all
// row bases are multiples of 4, r&3 == l16&3 -> per-thread constant.

// ---------------------------------------------------------------------------
// 256x256 TN GEMM, BK=32, 8 waves, 3-slot LDS rotation, counted vmcnt (T3/T4),
// T1 XCD swizzle, T2 LDS swizzle, and (r10) 4-PHASE K-window + T5 setprio:
// each K-step is split into 4 quadrant phases
//   {issue 1 staging load || ds_read subtile} -> s_barrier ->
//   setprio(1) -> 8 MFMA -> setprio(0)
// (m201 template scaled to BK=32; T5 pays only on phase-split schedules).
// vmcnt ledger UNCHANGED from the proven 3-slot kernel: tile kw+2's 4 loads
// issue spread across window kw's phases; at window start outstanding =
// 4 loads of tile kw+1 -> vmcnt(4) guarantees tile kw landed. Prologue
// (8 outstanding -> vmcnt(4) = tile0 landed) and tail (vmcnt(0) at last
// window; no staging in last 2 windows) re-derived identically.
// EXPSUM: writes exp(alpha*acc) bf16 and accumulates per-n' sums into rsum.
// ---------------------------------------------------------------------------
template<int BIAS_MODE, bool EXPSUM>
__global__ __launch_bounds__(512, 2) void gemm256_tn(
    const __hip_bfloat16* __restrict__ A, int lda, size_t sA,
    const __hip_bfloat16* __restrict__ B, int ldb, size_t sB,
    void* __restrict__ Zv, int ldz, size_t sZ,
    const float* __restrict__ bias,
    float alpha, int K,
    float* __restrict__ rsum)
{
  __shared__ __hip_bfloat16 ls[3 * 16384];   // 3 slots x (A 256x32 + B 256x32)
  const int t  = threadIdx.x;
  const int bb = blockIdx.z;

  // T1: bijective XCD swizzle (nbxy % 8 == 0 for all call sites)
  const int nbxy = gridDim.x * gridDim.y;
  const int borig = blockIdx.y * gridDim.x + blockIdx.x;
  const int cpx = nbxy >> 3;
  const int blog = (borig & 7) * cpx + (borig >> 3);
  const int bx = blog % gridDim.x;
  const int by = blog / gridDim.x;
  const int n0 = bx * 256;
  const int m0 = by * 256;

  const __hip_bfloat16* Ab = A + (size_t)bb * sA;
  const __hip_bfloat16* Bb = B + (size_t)bb * sB;

  const int lane = t & 63;
  const int quad = lane >> 4;
  const int l16  = lane & 15;
  const int wave = t >> 6;              // 0..7
  const int wm   = (wave >> 2) * 128;   // 2 wave-rows (m)
  const int wn   = (wave & 3) * 64;     // 4 wave-cols (n)
  const int qa   = (quad ^ (l16 & 3)) * 8;   // T2 read group

  // staging: 512 threads cover 128 rows x 32 k per call; 4 calls per k-step.
  const int rowc = t >> 2;              // 0..127
  const int kc   = ((t & 3) ^ (rowc & 3)) * 8;   // T2 pre-swizzled source col
  const __hip_bfloat16* ga0 = Ab + (size_t)(m0 + rowc) * lda + kc;
  const __hip_bfloat16* ga1 = Ab + (size_t)(m0 + rowc + 128) * lda + kc;
  const __hip_bfloat16* gb0 = Bb + (size_t)(n0 + rowc) * ldb + kc;
  const __hip_bfloat16* gb1 = Bb + (size_t)(n0 + rowc + 128) * ldb + kc;

  f32x4 acc[8][4] = {};

#define STAGE256(SLOT)                                                        \
  {                                                                           \
    __hip_bfloat16* lb = ls + (SLOT) * 16384 + t * 8;                         \
    async_cp16(ga0, lb);                                                      \
    async_cp16(ga1, lb + 4096);                                               \
    async_cp16(gb0, lb + 8192);                                               \
    async_cp16(gb1, lb + 12288);                                              \
    ga0 += 32; ga1 += 32; gb0 += 32; gb1 += 32;                               \
  }

#define RD_AF(I0)                                                             \
    _Pragma("unroll")                                                         \
    for (int i = 0; i < 4; ++i)                                               \
      af[(I0) + i] = *(const short8*)(bA + (wm + ((I0) + i) * 16 + l16) * 32 + qa);

#define RD_BF(J0)                                                             \
    _Pragma("unroll")                                                         \
    for (int j = 0; j < 2; ++j)                                               \
      bfr[(J0) + j] = *(const short8*)(bB + (wn + ((J0) + j) * 16 + l16) * 32 + qa);

#define PH_MFMA(I0, J0)                                                       \
    __builtin_amdgcn_s_setprio(1);                                            \
    _Pragma("unroll")                                                         \
    for (int i = 0; i < 4; ++i)                                               \
      _Pragma("unroll")                                                       \
      for (int j = 0; j < 2; ++j)                                             \
        acc[(I0) + i][(J0) + j] = __builtin_amdgcn_mfma_f32_16x16x32_bf16(    \
            af[(I0) + i], bfr[(J0) + j], acc[(I0) + i][(J0) + j], 0, 0, 0);   \
    __builtin_amdgcn_s_setprio(0);

  STAGE256(0);
  STAGE256(1);
  const int nk = K >> 5;
  for (int kw = 0; kw < nk; ++kw) {
    if (kw == nk - 1) {
      asm volatile("s_waitcnt vmcnt(0)" ::: "memory");
    } else {
      asm volatile("s_waitcnt vmcnt(4)" ::: "memory");
    }
    __builtin_amdgcn_s_barrier();
    const __hip_bfloat16* bA = ls + (kw % 3) * 16384;
    const __hip_bfloat16* bB = bA + 8192;
    const bool st = (kw + 2 < nk);
    __hip_bfloat16* lb = ls + ((kw + 2) % 3) * 16384 + t * 8;
    short8 af[8], bfr[4];
    // phase 0: stage load 0 || read af[0..3], bfr[0..1] -> MFMA Q(0,0)
    if (st) { async_cp16(ga0, lb);         ga0 += 32; }
    RD_AF(0); RD_BF(0);
    __builtin_amdgcn_s_barrier();
    PH_MFMA(0, 0);
    // phase 1: stage load 1 || read bfr[2..3] -> MFMA Q(0,1)
    if (st) { async_cp16(ga1, lb + 4096);  ga1 += 32; }
    RD_BF(2);
    __builtin_amdgcn_s_barrier();
    PH_MFMA(0, 2);
    // phase 2: stage load 2 || read af[4..7] -> MFMA Q(1,0)
    if (st) { async_cp16(gb0, lb + 8192);  gb0 += 32; }
    RD_AF(4);
    __builtin_amdgcn_s_barrier();
    PH_MFMA(4, 0);
    // phase 3: stage load 3 -> MFMA Q(1,1)
    if (st) { async_cp16(gb1, lb + 12288); gb1 += 32; }
    __builtin_amdgcn_s_barrier();
    PH_MFMA(4, 2);
  }

#undef STAGE256
#undef RD_AF
#undef RD_BF
#undef PH_MFMA

  if (EXPSUM) {
    __syncthreads();                     // waves done with LDS tiles
    float* rs = (float*)ls;              // 256 per-n partial sums
    if (t < 256) rs[t] = 0.f;
    __syncthreads();
    float lsum[4] = {0.f, 0.f, 0.f, 0.f};
#pragma unroll
    for (int i = 0; i < 8; ++i) {
#pragma unroll
      for (int j = 0; j < 4; ++j) {
        const int m = m0 + wm + i * 16 + quad * 4;
        const int n = n0 + wn + j * 16 + l16;
        f32x4 v = acc[i][j];
        v[0] = __expf(v[0] * alpha); v[1] = __expf(v[1] * alpha);
        v[2] = __expf(v[2] * alpha); v[3] = __expf(v[3] * alpha);
        lsum[j] += v[0] + v[1] + v[2] + v[3];
        union { u16 s[4]; uint2 q; } pk;
        pk.s[0] = f2bf(v[0]); pk.s[1] = f2bf(v[1]);
        pk.s[2] = f2bf(v[2]); pk.s[3] = f2bf(v[3]);
        *(uint2*)((__hip_bfloat16*)Zv + (size_t)bb * sZ + (size_t)n * ldz + m) = pk.q;
      }
    }
#pragma unroll
    for (int j = 0; j < 4; ++j)
      atomicAdd(&rs[wn + j * 16 + l16], lsum[j]);
    __syncthreads();
    if (t < 256) atomicAdd(rsum + (size_t)bb * 4096 + n0 + t, rs[t]);
    return;
  }

#pragma unroll
  for (int i = 0; i < 8; ++i) {
#pragma unroll
    for (int j = 0; j < 4; ++j) {
      const int m = m0 + wm + i * 16 + quad * 4;
      const int n = n0 + wn + j * 16 + l16;
      f32x4 v = acc[i][j];
      if (BIAS_MODE == 1) v += *(const f32x4*)(bias + m);
      else if (BIAS_MODE == 2) v += bias[n];
      v *= alpha;
      union { u16 s[4]; uint2 q; } pk;
      pk.s[0] = f2bf(v[0]); pk.s[1] = f2bf(v[1]);
      pk.s[2] = f2bf(v[2]); pk.s[3] = f2bf(v[3]);
      *(uint2*)((__hip_bfloat16*)Zv + (size_t)bb * sZ + (size_t)n * ldz + m) = pk.q;
    }
  }
}

// ---------------------------------------------------------------------------
// PV kernel: 128x128 TN GEMM, 8 waves (512 thr) = 2 waves/SIMD for TLP
// (r7/r8 post-mortem: PV is LATENCY-bound at 1 wave/SIMD; TLP is the lever).
// Each wave owns 64x32: af[4], bfr[2], 8 MFMA/window. Staging: 2 loads/lane
// per tile. 5-slot rotation, counted vmcnt: 3 tiles in flight x 2 loads ->
// windows wait vmcnt(6), tail 6/4/2/0. Same WAR ledger as r7 5-slot kernel.
// T2 swizzle + XCD-affinity remap (4 x-siblings share the 1 MB A panel).
// Grid (4, 32, Gc) = 256 blocks = 1/CU. LDS 5 x 16 KB = 80 KB.
// Fused FINAL epilogue: out[n'][m'] = xres + bias[n'] + acc / rsum[m'].
// ---------------------------------------------------------------------------
__global__ __launch_bounds__(512, 1) void gemm128x8w_final(
    const __hip_bfloat16* __restrict__ A, int lda, size_t sA,
    const __hip_bfloat16* __restrict__ B, int ldb, size_t sB,
    float* __restrict__ out, int ldz, size_t sZ,
    const float* __restrict__ bias,
    int K,
    const float* __restrict__ rsum,
    const float* __restrict__ xres)
{
  __shared__ __hip_bfloat16 ls[5 * 8192];   // 5 slots x (A 128x32 + B 128x32)
  const int t = threadIdx.x;

  int bx, by, bb;
  xcd_remap(bx, by, bb);
  const int n0 = bx * 128;                  // o rows
  const int m0 = by * 128;                  // attn-n rows

  const __hip_bfloat16* Ab = A + (size_t)bb * sA;
  const __hip_bfloat16* Bb = B + (size_t)bb * sB;

  const int lane = t & 63;
  const int quad = lane >> 4;
  const int l16  = lane & 15;
  const int wave = t >> 6;                  // 0..7
  const int wm   = (wave >> 2) * 64;        // 2 wave-rows (m), 64 each
  const int wn   = (wave & 3) * 32;         // 4 wave-cols (n), 32 each
  const int qa   = (quad ^ (l16 & 3)) * 8;  // T2 read group

  // staging: 512 threads cover 128 rows x 32 k in ONE call.
  const int rowc = t >> 2;                  // 0..127
  const int kc   = ((t & 3) ^ (rowc & 3)) * 8;  // T2 pre-swizzled source col
  const __hip_bfloat16* ga0 = Ab + (size_t)(m0 + rowc) * lda + kc;
  const __hip_bfloat16* gb0 = Bb + (size_t)(n0 + rowc) * ldb + kc;

  f32x4 acc[4][2] = {};

#define STAGEPV(SLOT)                                                         \
  {                                                                           \
    __hip_bfloat16* lb = ls + (SLOT) * 8192 + t * 8;                          \
    async_cp16(ga0, lb);                                                      \
    async_cp16(gb0, lb + 4096);                                               \
    ga0 += 32; gb0 += 32;                                                     \
  }

#define COMPUTEPV(SLOT)                                                       \
  {                                                                           \
    const __hip_bfloat16* bA = ls + (SLOT) * 8192;                            \
    const __hip_bfloat16* bB = bA + 4096;                                     \
    short8 af[4], bfr[2];                                                     \
    _Pragma("unroll")                                                         \
    for (int i = 0; i < 4; ++i)                                               \
      af[i] = *(const short8*)(bA + (wm + i * 16 + l16) * 32 + qa);           \
    _Pragma("unroll")                                                         \
    for (int j = 0; j < 2; ++j)                                               \
      bfr[j] = *(const short8*)(bB + (wn + j * 16 + l16) * 32 + qa);          \
    _Pragma("unroll")                                                         \
    for (int i = 0; i < 4; ++i)                                               \
      _Pragma("unroll")                                                       \
      for (int j = 0; j < 2; ++j)                                             \
        acc[i][j] = __builtin_amdgcn_mfma_f32_16x16x32_bf16(af[i], bfr[j],    \
                                                            acc[i][j], 0, 0, 0); \
  }

  STAGEPV(0);
  STAGEPV(1);
  STAGEPV(2);
  STAGEPV(3);
  const int nk = K >> 5;                 // 128 for all call sites (nk >= 5)
  for (int kw = 0; kw < nk - 4; ++kw) {
    asm volatile("s_waitcnt vmcnt(6)" ::: "memory");
    __builtin_amdgcn_s_barrier();
    STAGEPV((kw + 4) % 5);
    COMPUTEPV(kw % 5);
  }
  asm volatile("s_waitcnt vmcnt(6)" ::: "memory");
  __builtin_amdgcn_s_barrier();
  COMPUTEPV((nk - 4) % 5);
  asm volatile("s_waitcnt vmcnt(4)" ::: "memory");
  __builtin_amdgcn_s_barrier();
  COMPUTEPV((nk - 3) % 5);
  asm volatile("s_waitcnt vmcnt(2)" ::: "memory");
  __builtin_amdgcn_s_barrier();
  COMPUTEPV((nk - 2) % 5);
  asm volatile("s_waitcnt vmcnt(0)" ::: "memory");
  __builtin_amdgcn_s_barrier();
  COMPUTEPV((nk - 1) % 5);

#undef STAGEPV
#undef COMPUTEPV

#pragma unroll
  for (int i = 0; i < 4; ++i) {
#pragma unroll
    for (int j = 0; j < 2; ++j) {
      const int m = m0 + wm + i * 16 + quad * 4;
      const int n = n0 + wn + j * 16 + l16;
      f32x4 v = acc[i][j];
      const size_t zoff = (size_t)n * ldz + m;
      f32x4 rs = *(const f32x4*)(rsum + (size_t)bb * 4096 + m);
      f32x4 xx = *(const f32x4*)(xres + (size_t)bb * sZ + zoff);
      const float pbv = bias[n];
      v[0] = xx[0] + pbv + v[0] / rs[0];
      v[1] = xx[1] + pbv + v[1] / rs[1];
      v[2] = xx[2] + pbv + v[2] / rs[2];
      v[3] = xx[3] + pbv + v[3] / rs[3];
      *(f32x4*)(out + (size_t)bb * sZ + zoff) = v;
    }
  }
}

// ---------------------------------------------------------------------------
// Merged prep + gn_stats (independent inputs; one dispatch fewer).
// blocks [0,768): weight casts; 768: bias pack; [769,801): zero rsum;
// [801, 1057): gn_stats for batch-group bg = blk-801.
__global__ __launch_bounds__(256) void prep_stats(
    const float* __restrict__ qw, const float* __restrict__ kw,
    const float* __restrict__ pw, const float* __restrict__ qb,
    const float* __restrict__ kb,
    __hip_bfloat16* __restrict__ wqk, __hip_bfloat16* __restrict__ wp,
    float* __restrict__ bias_qk, float* __restrict__ rsum,
    const float* __restrict__ x, float2* __restrict__ stats) {
  const int blk = blockIdx.x;
  if (blk < 768) {
    const float* src = (blk < 256) ? qw : (blk < 512) ? kw : pw;
    __hip_bfloat16* dst = (blk < 256) ? wqk : (blk < 512) ? (wqk + 262144) : wp;
    const int i = ((blk & 255) * 256 + threadIdx.x) * 4;
    f32x4 v = *(const f32x4*)(src + i);
    union { u16 s4[4]; uint2 q; } pk;
    pk.s4[0] = f2bf(v[0]); pk.s4[1] = f2bf(v[1]);
    pk.s4[2] = f2bf(v[2]); pk.s4[3] = f2bf(v[3]);
    *(uint2*)(dst + i) = pk.q;
  } else if (blk == 768) {
    const int i = threadIdx.x * 4;
    *(f32x4*)(bias_qk + i) = *(const f32x4*)(qb + i);
    *(f32x4*)(bias_qk + 512 + i) = *(const f32x4*)(kb + i);
  } else if (blk < 801) {
    ((f32x4*)rsum)[(blk - 769) * 256 + threadIdx.x] = f32x4{0.f, 0.f, 0.f, 0.f};
  } else {
    const int bg = blk - 801;
    const f32x4* p = (const f32x4*)(x + (size_t)bg * 65536);
    float s = 0.f, s2 = 0.f;
    for (int i = threadIdx.x; i < 16384; i += 256) {
      f32x4 v = p[i];
      s  += v[0] + v[1] + v[2] + v[3];
      s2 += v[0]*v[0] + v[1]*v[1] + v[2]*v[2] + v[3]*v[3];
    }
    for (int o = 32; o > 0; o >>= 1) { s += __shfl_down(s, o); s2 += __shfl_down(s2, o); }
    __shared__ float wsum[4], wsum2[4];
    const int wave = threadIdx.x >> 6;
    if ((threadIdx.x & 63) == 0) { wsum[wave] = s; wsum2[wave] = s2; }
    __syncthreads();
    if (threadIdx.x == 0) {
      float S  = wsum[0] + wsum[1] + wsum[2] + wsum[3];
      float S2 = wsum2[0] + wsum2[1] + wsum2[2] + wsum2[3];
      float mu = S * (1.f / 65536.f);
      float var = S2 * (1.f / 65536.f) - mu * mu;
      stats[bg] = make_float2(mu, rsqrtf(var + 1e-6f));
    }
  }
}

// GroupNorm apply + transpose: x[b][c][n] fp32 -> r_t[b][n][c] bf16.
__global__ __launch_bounds__(256) void gn_apply(const float* __restrict__ x,
                                                const float2* __restrict__ stats,
                                                const float* __restrict__ gamma,
                                                const float* __restrict__ beta,
                                                __hip_bfloat16* __restrict__ rt) {
  const int b = blockIdx.y, n0 = blockIdx.x * 64;
  __shared__ float tile[64][65];
  const int t  = threadIdx.x;
  const int cl = t >> 2;
  const int q4 = (t & 3) * 4;
  for (int cc = 0; cc < 8; ++cc) {
    const int c = cc * 64 + cl;
    const float2 ms = stats[b * 32 + (c >> 4)];
    const float ga = gamma[c] * ms.y;
    const float be = beta[c] - ms.x * ga;
    const float* src = x + ((size_t)b * 512 + c) * 4096 + n0;
#pragma unroll
    for (int p = 0; p < 4; ++p) {
      f32x4 v = *(const f32x4*)(src + q4 + p * 16);
      tile[cl][q4 + p * 16 + 0] = fmaf(v[0], ga, be);
      tile[cl][q4 + p * 16 + 1] = fmaf(v[1], ga, be);
      tile[cl][q4 + p * 16 + 2] = fmaf(v[2], ga, be);
      tile[cl][q4 + p * 16 + 3] = fmaf(v[3], ga, be);
    }
    __syncthreads();
    const int nw = t >> 2;
    const int cw = (t & 3) * 16;
    union { u16 s[16]; uint4 q[2]; } pk;
#pragma unroll
    for (int j = 0; j < 16; ++j) pk.s[j] = f2bf(tile[cw + j][nw]);
    __hip_bfloat16* dst = rt + ((size_t)b * 4096 + n0 + nw) * 512 + cc * 64 + cw;
    *(uint4*)dst = pk.q[0];
    *((uint4*)dst + 1) = pk.q[1];
    __syncthreads();
  }
}

// ---------------------------------------------------------------------------
extern "C" void kernel_launch(void* const* d_in, const int* in_sizes, int n_in,
                              void* d_out, int out_size, void* d_ws, size_t ws_size,
                              hipStream_t stream) {
  const float* x     = (const float*)d_in[0];
  const float* gamma = (const float*)d_in[1];
  const float* beta  = (const float*)d_in[2];
  const float* q_w   = (const float*)d_in[3];
  const float* q_b   = (const float*)d_in[4];
  const float* k_w   = (const float*)d_in[5];
  const float* k_b   = (const float*)d_in[6];
  const float* p_w   = (const float*)d_in[7];
  const float* p_b   = (const float*)d_in[8];
  float* out = (float*)d_out;

  constexpr int B = 8, C = 512, N = 4096;
  constexpr size_t NC = (size_t)N * C;
  constexpr size_t NN = (size_t)N * N;

  char* ws = (char*)d_ws;
  size_t off = 0;
  auto alloc = [&](size_t bytes) {
    void* p = ws + off;
    off += (bytes + 255) & ~(size_t)255;
    return p;
  };

  __hip_bfloat16* wqk = (__hip_bfloat16*)alloc((size_t)1024 * 512 * 2);
  __hip_bfloat16* wp  = (__hip_bfloat16*)alloc((size_t)C * C * 2);
  float* bias_qk      = (float*)alloc(1024 * 4);
  float2* stats       = (float2*)alloc((size_t)B * 32 * sizeof(float2));
  float* rsum         = (float*)alloc((size_t)B * N * 4);
  __hip_bfloat16* rt  = (__hip_bfloat16*)alloc(B * NC * 2);               // [b][n][c]
  __hip_bfloat16* qkt = (__hip_bfloat16*)alloc(B * (size_t)N * 1024 * 2); // [b][n][q|k]
  __hip_bfloat16* wpv = (__hip_bfloat16*)alloc(B * NC * 2);               // [b][o][m]
  const size_t base_off = off;

  const size_t attn_b_bytes = NN * 2;
  size_t avail = (ws_size > base_off) ? ws_size - base_off : 0;
  int G = 4;
  if (avail < 4 * attn_b_bytes) G = 2;
  if (avail < 2 * attn_b_bytes) G = 1;
  __hip_bfloat16* attn = (__hip_bfloat16*)alloc(attn_b_bytes * G);

  const dim3 blk(256);
  const dim3 blk512(512);
  const float scale = 0.044194173824159216f;  // 512^-0.5

  prep_stats<<<dim3(801 + B * 32), blk, 0, stream>>>(
      q_w, k_w, p_w, q_b, k_b, wqk, wp, bias_qk, rsum, x, stats);

  gn_apply<<<dim3(64, B), blk, 0, stream>>>(x, stats, gamma, beta, rt);

  // merged q|k projection: qkt[b][n][m'] (m'<512: q+qb, m'>=512: k+kb)
  gemm256_tn<1, false><<<dim3(16, 4, B), blk512, 0, stream>>>(
      wqk, C, 0, rt, C, NC, qkt, 1024, (size_t)N * 1024,
      bias_qk, 1.f, C, nullptr);

  // wpv[b][o][m] = sum_c wp[o][c] * k_hat[m][c]
  gemm256_tn<0, false><<<dim3(2, 16, B), blk512, 0, stream>>>(
      qkt + 512, 1024, (size_t)N * 1024, wp, C, 0,
      wpv, N, NC, nullptr, 1.f, C, nullptr);

  for (int b0 = 0; b0 < B; ) {
    const int Gc = (B - b0 < G) ? (B - b0) : G;

    // p[n][m] = exp(scale * sum_c k_hat[m][c] * q_hat[n][c]); rsum[n] += ...
    gemm256_tn<0, true><<<dim3(16, 16, Gc), blk512, 0, stream>>>(
        qkt + (size_t)b0 * N * 1024 + 512, 1024, (size_t)N * 1024,
        qkt + (size_t)b0 * N * 1024,       1024, (size_t)N * 1024,
        attn, N, NN, nullptr, scale, C, rsum + (size_t)b0 * N);

    // out[o][n] = x + pb[o] + (sum_m wpv[o][m] * p[n][m]) / rsum[n]
    gemm128x8w_final<<<dim3(4, 32, Gc), blk512, 0, stream>>>(
        attn, N, NN, wpv + (size_t)b0 * NC, N, NC,
        out + (size_t)b0 * NC, N, NC, p_b, N,
        rsum + (size_t)b0 * N, x + (size_t)b0 * NC);

    b0 += Gc;
  }
}

// Round 11
// 638.987 us; speedup vs baseline: 1.0608x; 1.0608x over previous
//
#include <hip/hip_runtime.h>
#include <hip/hip_bf16.h>
#include <cstdint>

#define DEVI __device__ __forceinline__

typedef __attribute__((ext_vector_type(8))) short short8;
typedef __attribute__((ext_vector_type(4))) float f32x4;
typedef unsigned int u32;
typedef unsigned short u16;

DEVI u16 f2bf(float f) {
  __hip_bfloat16 h = __float2bfloat16(f);
  return *reinterpret_cast<u16*>(&h);
}

// async global->LDS, 16B per lane. LDS dest must be wave-uniform base + lane*16.
DEVI void async_cp16(const __hip_bfloat16* g, __hip_bfloat16* l) {
  __builtin_amdgcn_global_load_lds(
      (const __attribute__((address_space(1))) u32*)(uintptr_t)g,
      (__attribute__((address_space(3))) u32*)(uintptr_t)l, 16, 0, 0);
}

// XCD-affinity bijective block remap (PV only — measured r6: FETCH 148->74 MB):
// blocks sharing an A-panel (same y,z; all x) land on the SAME XCD at
// consecutive slots, so the panel is served from that XCD's L2 on re-reads.
// HW assigns xcd ~ dispatch_id % 8. Requires gy*gz % 8 == 0.
DEVI void xcd_remap(int& bx, int& by, int& bz) {
  const int gx = gridDim.x, gy = gridDim.y;
  const int d = blockIdx.x + gx * (blockIdx.y + gridDim.y * blockIdx.z);
  const int idx = d >> 3;
  const int g = (d & 7) + 8 * (idx / gx);
  bx = idx % gx;
  by = g % gy;
  bz = g / gy;
}

// T2 swizzle (rule #21: LDS linear for global_load_lds; SOURCE column group
// pre-swizzled; READ uses the same XOR): LDS[row][g] = A[row][g ^ (row&3)]
// (g = 16B k-group 0..3). Read of A[r][quad] -> group quad ^ (r&3); since all
// row bases are multiples of 4, r&3 == l16&3 -> per-thread constant.

// ---------------------------------------------------------------------------
// 256x256 TN GEMM, BK=32, 8 waves, 3-slot LDS rotation, counted vmcnt (T3/T4),
// T1 XCD swizzle, T2 LDS swizzle, 4-PHASE K-window + T5 setprio (r10; QK^T
// measured ~61.5 vs 63.5 coarse).
// vmcnt ledger: tile kw+2's 4 loads issue spread across window kw's phases;
// at window start outstanding = 4 loads of tile kw+1 -> vmcnt(4) guarantees
// tile kw landed. Prologue: 8 outstanding -> vmcnt(4) = tile0 landed. Tail:
// vmcnt(0) at last window; no staging in last 2 windows.
// EXPSUM: writes exp(alpha*acc) bf16 and accumulates per-n' sums into rsum.
// ---------------------------------------------------------------------------
template<int BIAS_MODE, bool EXPSUM>
__global__ __launch_bounds__(512, 2) void gemm256_tn(
    const __hip_bfloat16* __restrict__ A, int lda, size_t sA,
    const __hip_bfloat16* __restrict__ B, int ldb, size_t sB,
    void* __restrict__ Zv, int ldz, size_t sZ,
    const float* __restrict__ bias,
    float alpha, int K,
    float* __restrict__ rsum)
{
  __shared__ __hip_bfloat16 ls[3 * 16384];   // 3 slots x (A 256x32 + B 256x32)
  const int t  = threadIdx.x;
  const int bb = blockIdx.z;

  // T1: bijective XCD swizzle (nbxy % 8 == 0 for all call sites)
  const int nbxy = gridDim.x * gridDim.y;
  const int borig = blockIdx.y * gridDim.x + blockIdx.x;
  const int cpx = nbxy >> 3;
  const int blog = (borig & 7) * cpx + (borig >> 3);
  const int bx = blog % gridDim.x;
  const int by = blog / gridDim.x;
  const int n0 = bx * 256;
  const int m0 = by * 256;

  const __hip_bfloat16* Ab = A + (size_t)bb * sA;
  const __hip_bfloat16* Bb = B + (size_t)bb * sB;

  const int lane = t & 63;
  const int quad = lane >> 4;
  const int l16  = lane & 15;
  const int wave = t >> 6;              // 0..7
  const int wm   = (wave >> 2) * 128;   // 2 wave-rows (m)
  const int wn   = (wave & 3) * 64;     // 4 wave-cols (n)
  const int qa   = (quad ^ (l16 & 3)) * 8;   // T2 read group

  // staging: 512 threads cover 128 rows x 32 k per call; 4 calls per k-step.
  const int rowc = t >> 2;              // 0..127
  const int kc   = ((t & 3) ^ (rowc & 3)) * 8;   // T2 pre-swizzled source col
  const __hip_bfloat16* ga0 = Ab + (size_t)(m0 + rowc) * lda + kc;
  const __hip_bfloat16* ga1 = Ab + (size_t)(m0 + rowc + 128) * lda + kc;
  const __hip_bfloat16* gb0 = Bb + (size_t)(n0 + rowc) * ldb + kc;
  const __hip_bfloat16* gb1 = Bb + (size_t)(n0 + rowc + 128) * ldb + kc;

  f32x4 acc[8][4] = {};

#define STAGE256(SLOT)                                                        \
  {                                                                           \
    __hip_bfloat16* lb = ls + (SLOT) * 16384 + t * 8;                         \
    async_cp16(ga0, lb);                                                      \
    async_cp16(ga1, lb + 4096);                                               \
    async_cp16(gb0, lb + 8192);                                               \
    async_cp16(gb1, lb + 12288);                                              \
    ga0 += 32; ga1 += 32; gb0 += 32; gb1 += 32;                               \
  }

#define RD_AF(I0)                                                             \
    _Pragma("unroll")                                                         \
    for (int i = 0; i < 4; ++i)                                               \
      af[(I0) + i] = *(const short8*)(bA + (wm + ((I0) + i) * 16 + l16) * 32 + qa);

#define RD_BF(J0)                                                             \
    _Pragma("unroll")                                                         \
    for (int j = 0; j < 2; ++j)                                               \
      bfr[(J0) + j] = *(const short8*)(bB + (wn + ((J0) + j) * 16 + l16) * 32 + qa);

#define PH_MFMA(I0, J0)                                                       \
    __builtin_amdgcn_s_setprio(1);                                            \
    _Pragma("unroll")                                                         \
    for (int i = 0; i < 4; ++i)                                               \
      _Pragma("unroll")                                                       \
      for (int j = 0; j < 2; ++j)                                             \
        acc[(I0) + i][(J0) + j] = __builtin_amdgcn_mfma_f32_16x16x32_bf16(    \
            af[(I0) + i], bfr[(J0) + j], acc[(I0) + i][(J0) + j], 0, 0, 0);   \
    __builtin_amdgcn_s_setprio(0);

  STAGE256(0);
  STAGE256(1);
  const int nk = K >> 5;
  for (int kw = 0; kw < nk; ++kw) {
    if (kw == nk - 1) {
      asm volatile("s_waitcnt vmcnt(0)" ::: "memory");
    } else {
      asm volatile("s_waitcnt vmcnt(4)" ::: "memory");
    }
    __builtin_amdgcn_s_barrier();
    const __hip_bfloat16* bA = ls + (kw % 3) * 16384;
    const __hip_bfloat16* bB = bA + 8192;
    const bool st = (kw + 2 < nk);
    __hip_bfloat16* lb = ls + ((kw + 2) % 3) * 16384 + t * 8;
    short8 af[8], bfr[4];
    // phase 0: stage load 0 || read af[0..3], bfr[0..1] -> MFMA Q(0,0)
    if (st) { async_cp16(ga0, lb);         ga0 += 32; }
    RD_AF(0); RD_BF(0);
    __builtin_amdgcn_s_barrier();
    PH_MFMA(0, 0);
    // phase 1: stage load 1 || read bfr[2..3] -> MFMA Q(0,1)
    if (st) { async_cp16(ga1, lb + 4096);  ga1 += 32; }
    RD_BF(2);
    __builtin_amdgcn_s_barrier();
    PH_MFMA(0, 2);
    // phase 2: stage load 2 || read af[4..7] -> MFMA Q(1,0)
    if (st) { async_cp16(gb0, lb + 8192);  gb0 += 32; }
    RD_AF(4);
    __builtin_amdgcn_s_barrier();
    PH_MFMA(4, 0);
    // phase 3: stage load 3 -> MFMA Q(1,1)
    if (st) { async_cp16(gb1, lb + 12288); gb1 += 32; }
    __builtin_amdgcn_s_barrier();
    PH_MFMA(4, 2);
  }

#undef STAGE256
#undef RD_AF
#undef RD_BF
#undef PH_MFMA

  if (EXPSUM) {
    __syncthreads();                     // waves done with LDS tiles
    float* rs = (float*)ls;              // 256 per-n partial sums
    if (t < 256) rs[t] = 0.f;
    __syncthreads();
    float lsum[4] = {0.f, 0.f, 0.f, 0.f};
#pragma unroll
    for (int i = 0; i < 8; ++i) {
#pragma unroll
      for (int j = 0; j < 4; ++j) {
        const int m = m0 + wm + i * 16 + quad * 4;
        const int n = n0 + wn + j * 16 + l16;
        f32x4 v = acc[i][j];
        v[0] = __expf(v[0] * alpha); v[1] = __expf(v[1] * alpha);
        v[2] = __expf(v[2] * alpha); v[3] = __expf(v[3] * alpha);
        lsum[j] += v[0] + v[1] + v[2] + v[3];
        union { u16 s[4]; uint2 q; } pk;
        pk.s[0] = f2bf(v[0]); pk.s[1] = f2bf(v[1]);
        pk.s[2] = f2bf(v[2]); pk.s[3] = f2bf(v[3]);
        *(uint2*)((__hip_bfloat16*)Zv + (size_t)bb * sZ + (size_t)n * ldz + m) = pk.q;
      }
    }
#pragma unroll
    for (int j = 0; j < 4; ++j)
      atomicAdd(&rs[wn + j * 16 + l16], lsum[j]);
    __syncthreads();
    if (t < 256) atomicAdd(rsum + (size_t)bb * 4096 + n0 + t, rs[t]);
    return;
  }

#pragma unroll
  for (int i = 0; i < 8; ++i) {
#pragma unroll
    for (int j = 0; j < 4; ++j) {
      const int m = m0 + wm + i * 16 + quad * 4;
      const int n = n0 + wn + j * 16 + l16;
      f32x4 v = acc[i][j];
      if (BIAS_MODE == 1) v += *(const f32x4*)(bias + m);
      else if (BIAS_MODE == 2) v += bias[n];
      v *= alpha;
      union { u16 s[4]; uint2 q; } pk;
      pk.s[0] = f2bf(v[0]); pk.s[1] = f2bf(v[1]);
      pk.s[2] = f2bf(v[2]); pk.s[3] = f2bf(v[3]);
      *(uint2*)((__hip_bfloat16*)Zv + (size_t)bb * sZ + (size_t)n * ldz + m) = pk.q;
    }
  }
}

// ---------------------------------------------------------------------------
// PV kernel: 128x128 TN GEMM, 8 waves (512 thr) = 2 waves/SIMD for TLP
// (r7/r8 post-mortem: PV is LATENCY-bound at 1 wave/SIMD; TLP is the lever).
// With G=4 the grid is (4,32,4) = 512 blocks = 2 blocks/CU co-resident
// (VGPR 52, LDS 2x80KB = exactly the 160KB pool) -> 4 waves/SIMD.
// Each wave owns 64x32: af[4], bfr[2], 8 MFMA/window. Staging: 2 loads/lane
// per tile. 5-slot rotation, counted vmcnt: 3 tiles in flight x 2 loads ->
// windows wait vmcnt(6), tail 6/4/2/0. Same WAR ledger as r7 5-slot kernel.
// T2 swizzle + XCD-affinity remap (4 x-siblings share the 1 MB A panel).
// Fused FINAL epilogue: out[n'][m'] = xres + bias[n'] + acc / rsum[m'].
// ---------------------------------------------------------------------------
__global__ __launch_bounds__(512, 1) void gemm128x8w_final(
    const __hip_bfloat16* __restrict__ A, int lda, size_t sA,
    const __hip_bfloat16* __restrict__ B, int ldb, size_t sB,
    float* __restrict__ out, int ldz, size_t sZ,
    const float* __restrict__ bias,
    int K,
    const float* __restrict__ rsum,
    const float* __restrict__ xres)
{
  __shared__ __hip_bfloat16 ls[5 * 8192];   // 5 slots x (A 128x32 + B 128x32)
  const int t = threadIdx.x;

  int bx, by, bb;
  xcd_remap(bx, by, bb);
  const int n0 = bx * 128;                  // o rows
  const int m0 = by * 128;                  // attn-n rows

  const __hip_bfloat16* Ab = A + (size_t)bb * sA;
  const __hip_bfloat16* Bb = B + (size_t)bb * sB;

  const int lane = t & 63;
  const int quad = lane >> 4;
  const int l16  = lane & 15;
  const int wave = t >> 6;                  // 0..7
  const int wm   = (wave >> 2) * 64;        // 2 wave-rows (m), 64 each
  const int wn   = (wave & 3) * 32;         // 4 wave-cols (n), 32 each
  const int qa   = (quad ^ (l16 & 3)) * 8;  // T2 read group

  // staging: 512 threads cover 128 rows x 32 k in ONE call.
  const int rowc = t >> 2;                  // 0..127
  const int kc   = ((t & 3) ^ (rowc & 3)) * 8;  // T2 pre-swizzled source col
  const __hip_bfloat16* ga0 = Ab + (size_t)(m0 + rowc) * lda + kc;
  const __hip_bfloat16* gb0 = Bb + (size_t)(n0 + rowc) * ldb + kc;

  f32x4 acc[4][2] = {};

#define STAGEPV(SLOT)                                                         \
  {                                                                           \
    __hip_bfloat16* lb = ls + (SLOT) * 8192 + t * 8;                          \
    async_cp16(ga0, lb);                                                      \
    async_cp16(gb0, lb + 4096);                                               \
    ga0 += 32; gb0 += 32;                                                     \
  }

#define COMPUTEPV(SLOT)                                                       \
  {                                                                           \
    const __hip_bfloat16* bA = ls + (SLOT) * 8192;                            \
    const __hip_bfloat16* bB = bA + 4096;                                     \
    short8 af[4], bfr[2];                                                     \
    _Pragma("unroll")                                                         \
    for (int i = 0; i < 4; ++i)                                               \
      af[i] = *(const short8*)(bA + (wm + i * 16 + l16) * 32 + qa);           \
    _Pragma("unroll")                                                         \
    for (int j = 0; j < 2; ++j)                                               \
      bfr[j] = *(const short8*)(bB + (wn + j * 16 + l16) * 32 + qa);          \
    _Pragma("unroll")                                                         \
    for (int i = 0; i < 4; ++i)                                               \
      _Pragma("unroll")                                                       \
      for (int j = 0; j < 2; ++j)                                             \
        acc[i][j] = __builtin_amdgcn_mfma_f32_16x16x32_bf16(af[i], bfr[j],    \
                                                            acc[i][j], 0, 0, 0); \
  }

  STAGEPV(0);
  STAGEPV(1);
  STAGEPV(2);
  STAGEPV(3);
  const int nk = K >> 5;                 // 128 for all call sites (nk >= 5)
  for (int kw = 0; kw < nk - 4; ++kw) {
    asm volatile("s_waitcnt vmcnt(6)" ::: "memory");
    __builtin_amdgcn_s_barrier();
    STAGEPV((kw + 4) % 5);
    COMPUTEPV(kw % 5);
  }
  asm volatile("s_waitcnt vmcnt(6)" ::: "memory");
  __builtin_amdgcn_s_barrier();
  COMPUTEPV((nk - 4) % 5);
  asm volatile("s_waitcnt vmcnt(4)" ::: "memory");
  __builtin_amdgcn_s_barrier();
  COMPUTEPV((nk - 3) % 5);
  asm volatile("s_waitcnt vmcnt(2)" ::: "memory");
  __builtin_amdgcn_s_barrier();
  COMPUTEPV((nk - 2) % 5);
  asm volatile("s_waitcnt vmcnt(0)" ::: "memory");
  __builtin_amdgcn_s_barrier();
  COMPUTEPV((nk - 1) % 5);

#undef STAGEPV
#undef COMPUTEPV

#pragma unroll
  for (int i = 0; i < 4; ++i) {
#pragma unroll
    for (int j = 0; j < 2; ++j) {
      const int m = m0 + wm + i * 16 + quad * 4;
      const int n = n0 + wn + j * 16 + l16;
      f32x4 v = acc[i][j];
      const size_t zoff = (size_t)n * ldz + m;
      f32x4 rs = *(const f32x4*)(rsum + (size_t)bb * 4096 + m);
      f32x4 xx = *(const f32x4*)(xres + (size_t)bb * sZ + zoff);
      const float pbv = bias[n];
      v[0] = xx[0] + pbv + v[0] / rs[0];
      v[1] = xx[1] + pbv + v[1] / rs[1];
      v[2] = xx[2] + pbv + v[2] / rs[2];
      v[3] = xx[3] + pbv + v[3] / rs[3];
      *(f32x4*)(out + (size_t)bb * sZ + zoff) = v;
    }
  }
}

// ---------------------------------------------------------------------------
// Merged prep + gn_stats (independent inputs; one dispatch fewer).
// blocks [0,768): weight casts; 768: bias pack; [769,801): zero rsum;
// [801, 1057): gn_stats for batch-group bg = blk-801.
__global__ __launch_bounds__(256) void prep_stats(
    const float* __restrict__ qw, const float* __restrict__ kw,
    const float* __restrict__ pw, const float* __restrict__ qb,
    const float* __restrict__ kb,
    __hip_bfloat16* __restrict__ wqk, __hip_bfloat16* __restrict__ wp,
    float* __restrict__ bias_qk, float* __restrict__ rsum,
    const float* __restrict__ x, float2* __restrict__ stats) {
  const int blk = blockIdx.x;
  if (blk < 768) {
    const float* src = (blk < 256) ? qw : (blk < 512) ? kw : pw;
    __hip_bfloat16* dst = (blk < 256) ? wqk : (blk < 512) ? (wqk + 262144) : wp;
    const int i = ((blk & 255) * 256 + threadIdx.x) * 4;
    f32x4 v = *(const f32x4*)(src + i);
    union { u16 s4[4]; uint2 q; } pk;
    pk.s4[0] = f2bf(v[0]); pk.s4[1] = f2bf(v[1]);
    pk.s4[2] = f2bf(v[2]); pk.s4[3] = f2bf(v[3]);
    *(uint2*)(dst + i) = pk.q;
  } else if (blk == 768) {
    const int i = threadIdx.x * 4;
    *(f32x4*)(bias_qk + i) = *(const f32x4*)(qb + i);
    *(f32x4*)(bias_qk + 512 + i) = *(const f32x4*)(kb + i);
  } else if (blk < 801) {
    ((f32x4*)rsum)[(blk - 769) * 256 + threadIdx.x] = f32x4{0.f, 0.f, 0.f, 0.f};
  } else {
    const int bg = blk - 801;
    const f32x4* p = (const f32x4*)(x + (size_t)bg * 65536);
    float s = 0.f, s2 = 0.f;
    for (int i = threadIdx.x; i < 16384; i += 256) {
      f32x4 v = p[i];
      s  += v[0] + v[1] + v[2] + v[3];
      s2 += v[0]*v[0] + v[1]*v[1] + v[2]*v[2] + v[3]*v[3];
    }
    for (int o = 32; o > 0; o >>= 1) { s += __shfl_down(s, o); s2 += __shfl_down(s2, o); }
    __shared__ float wsum[4], wsum2[4];
    const int wave = threadIdx.x >> 6;
    if ((threadIdx.x & 63) == 0) { wsum[wave] = s; wsum2[wave] = s2; }
    __syncthreads();
    if (threadIdx.x == 0) {
      float S  = wsum[0] + wsum[1] + wsum[2] + wsum[3];
      float S2 = wsum2[0] + wsum2[1] + wsum2[2] + wsum2[3];
      float mu = S * (1.f / 65536.f);
      float var = S2 * (1.f / 65536.f) - mu * mu;
      stats[bg] = make_float2(mu, rsqrtf(var + 1e-6f));
    }
  }
}

// GroupNorm apply + transpose: x[b][c][n] fp32 -> r_t[b][n][c] bf16.
__global__ __launch_bounds__(256) void gn_apply(const float* __restrict__ x,
                                                const float2* __restrict__ stats,
                                                const float* __restrict__ gamma,
                                                const float* __restrict__ beta,
                                                __hip_bfloat16* __restrict__ rt) {
  const int b = blockIdx.y, n0 = blockIdx.x * 64;
  __shared__ float tile[64][65];
  const int t  = threadIdx.x;
  const int cl = t >> 2;
  const int q4 = (t & 3) * 4;
  for (int cc = 0; cc < 8; ++cc) {
    const int c = cc * 64 + cl;
    const float2 ms = stats[b * 32 + (c >> 4)];
    const float ga = gamma[c] * ms.y;
    const float be = beta[c] - ms.x * ga;
    const float* src = x + ((size_t)b * 512 + c) * 4096 + n0;
#pragma unroll
    for (int p = 0; p < 4; ++p) {
      f32x4 v = *(const f32x4*)(src + q4 + p * 16);
      tile[cl][q4 + p * 16 + 0] = fmaf(v[0], ga, be);
      tile[cl][q4 + p * 16 + 1] = fmaf(v[1], ga, be);
      tile[cl][q4 + p * 16 + 2] = fmaf(v[2], ga, be);
      tile[cl][q4 + p * 16 + 3] = fmaf(v[3], ga, be);
    }
    __syncthreads();
    const int nw = t >> 2;
    const int cw = (t & 3) * 16;
    union { u16 s[16]; uint4 q[2]; } pk;
#pragma unroll
    for (int j = 0; j < 16; ++j) pk.s[j] = f2bf(tile[cw + j][nw]);
    __hip_bfloat16* dst = rt + ((size_t)b * 4096 + n0 + nw) * 512 + cc * 64 + cw;
    *(uint4*)dst = pk.q[0];
    *((uint4*)dst + 1) = pk.q[1];
    __syncthreads();
  }
}

// ---------------------------------------------------------------------------
extern "C" void kernel_launch(void* const* d_in, const int* in_sizes, int n_in,
                              void* d_out, int out_size, void* d_ws, size_t ws_size,
                              hipStream_t stream) {
  const float* x     = (const float*)d_in[0];
  const float* gamma = (const float*)d_in[1];
  const float* beta  = (const float*)d_in[2];
  const float* q_w   = (const float*)d_in[3];
  const float* q_b   = (const float*)d_in[4];
  const float* k_w   = (const float*)d_in[5];
  const float* k_b   = (const float*)d_in[6];
  const float* p_w   = (const float*)d_in[7];
  const float* p_b   = (const float*)d_in[8];
  float* out = (float*)d_out;

  constexpr int B = 8, C = 512, N = 4096;
  constexpr size_t NC = (size_t)N * C;
  constexpr size_t NN = (size_t)N * N;

  char* ws = (char*)d_ws;
  size_t off = 0;
  auto alloc = [&](size_t bytes) {
    void* p = ws + off;
    off += (bytes + 255) & ~(size_t)255;
    return p;
  };

  __hip_bfloat16* wqk = (__hip_bfloat16*)alloc((size_t)1024 * 512 * 2);
  __hip_bfloat16* wp  = (__hip_bfloat16*)alloc((size_t)C * C * 2);
  float* bias_qk      = (float*)alloc(1024 * 4);
  float2* stats       = (float2*)alloc((size_t)B * 32 * sizeof(float2));
  float* rsum         = (float*)alloc((size_t)B * N * 4);
  __hip_bfloat16* qkt = (__hip_bfloat16*)alloc(B * (size_t)N * 1024 * 2); // [b][n][q|k]
  __hip_bfloat16* wpv = (__hip_bfloat16*)alloc(B * NC * 2);               // [b][o][m]
  const size_t base_off = off;   // ~98 MB — rt is NOT counted here

  // rt (32 MB) ALIASES the attn region: rt is last read by the qk-proj
  // dispatch; attn is first written by the QK^T dispatch, which is
  // stream-ordered after it. Freeing these 32 MB from the base unlocks
  // G=4 (2 chunks instead of 4; PV grid 512 blocks = 2 blocks/CU TLP).
  const size_t attn_b_bytes = NN * 2;
  size_t avail = (ws_size > base_off) ? ws_size - base_off : 0;
  int G = 4;
  if (avail < 4 * attn_b_bytes) G = 2;
  if (avail < 2 * attn_b_bytes) G = 1;
  __hip_bfloat16* attn = (__hip_bfloat16*)alloc(attn_b_bytes * G);
  __hip_bfloat16* rt   = attn;   // alias: rt fits in attn (G*32MB >= 32MB)

  const dim3 blk(256);
  const dim3 blk512(512);
  const float scale = 0.044194173824159216f;  // 512^-0.5

  prep_stats<<<dim3(801 + B * 32), blk, 0, stream>>>(
      q_w, k_w, p_w, q_b, k_b, wqk, wp, bias_qk, rsum, x, stats);

  gn_apply<<<dim3(64, B), blk, 0, stream>>>(x, stats, gamma, beta, rt);

  // merged q|k projection: qkt[b][n][m'] (m'<512: q+qb, m'>=512: k+kb)
  gemm256_tn<1, false><<<dim3(16, 4, B), blk512, 0, stream>>>(
      wqk, C, 0, rt, C, NC, qkt, 1024, (size_t)N * 1024,
      bias_qk, 1.f, C, nullptr);

  // wpv[b][o][m] = sum_c wp[o][c] * k_hat[m][c]
  gemm256_tn<0, false><<<dim3(2, 16, B), blk512, 0, stream>>>(
      qkt + 512, 1024, (size_t)N * 1024, wp, C, 0,
      wpv, N, NC, nullptr, 1.f, C, nullptr);

  for (int b0 = 0; b0 < B; ) {
    const int Gc = (B - b0 < G) ? (B - b0) : G;

    // p[n][m] = exp(scale * sum_c k_hat[m][c] * q_hat[n][c]); rsum[n] += ...
    gemm256_tn<0, true><<<dim3(16, 16, Gc), blk512, 0, stream>>>(
        qkt + (size_t)b0 * N * 1024 + 512, 1024, (size_t)N * 1024,
        qkt + (size_t)b0 * N * 1024,       1024, (size_t)N * 1024,
        attn, N, NN, nullptr, scale, C, rsum + (size_t)b0 * N);

    // out[o][n] = x + pb[o] + (sum_m wpv[o][m] * p[n][m]) / rsum[n]
    gemm128x8w_final<<<dim3(4, 32, Gc), blk512, 0, stream>>>(
        attn, N, NN, wpv + (size_t)b0 * NC, N, NC,
        out + (size_t)b0 * NC, N, NC, p_b, N,
        rsum + (size_t)b0 * N, x + (size_t)b0 * NC);

    b0 += Gc;
  }
}